// Round 20
// baseline (414.169 us; speedup 1.0000x reference)
//
#include <hip/hip_runtime.h>

#define N_NODES 50000
#define N_EDGES 600000
#define N_GRAPHS 500
#define F 128

typedef short bf16x8 __attribute__((ext_vector_type(8)));
typedef float f32x4 __attribute__((ext_vector_type(4)));
union U4H8 { uint4 u; bf16x8 h; };

// ---- bf16 helpers (RNE) ----
__device__ inline unsigned pk_bf16(float a, float b) {
    unsigned ua = __float_as_uint(a), ub = __float_as_uint(b);
    ua = (ua + 0x7fffu + ((ua >> 16) & 1u)) >> 16;
    ub = (ub + 0x7fffu + ((ub >> 16) & 1u)) >> 16;
    return ua | (ub << 16);
}
__device__ inline float bf16_rnd(float x) {
    unsigned u = __float_as_uint(x);
    u = (u + 0x7fffu + ((u >> 16) & 1u)) & 0xffff0000u;
    return __uint_as_float(u);
}
__device__ inline unsigned short bf16_1(float a) {
    unsigned ua = __float_as_uint(a);
    return (unsigned short)((ua + 0x7fffu + ((ua >> 16) & 1u)) >> 16);
}
#define BF_LO(u) __uint_as_float((u) << 16)
#define BF_HI(u) __uint_as_float((u) & 0xffff0000u)

#define G_CVT  3125
#define G_HIST 2344
#define G_PREPW 24
#define G_BND  196

// ====== merged prep: x->bf16 | dst histogram | W split-pack | pool segment bounds ======
__global__ __launch_bounds__(256) void k_prep(const float* __restrict__ x, unsigned short* __restrict__ xb,
                                              const int* __restrict__ dst, int* __restrict__ cnt,
                                              const float* __restrict__ W1, const float* __restrict__ W2,
                                              const float* __restrict__ W3,
                                              uint4* __restrict__ Whi, uint4* __restrict__ Wlo,
                                              const int* __restrict__ batch, int* __restrict__ gs) {
    int b = blockIdx.x, tid = threadIdx.x;
    if (b < G_CVT) {
        int idx = b * 256 + tid;
        if (idx < N_NODES * F / 8) {
            const float4* xr = (const float4*)(x + (size_t)idx * 8);
            float4 a = xr[0], c = xr[1];
            uint4 o;
            o.x = pk_bf16(a.x, a.y); o.y = pk_bf16(a.z, a.w);
            o.z = pk_bf16(c.x, c.y); o.w = pk_bf16(c.z, c.w);
            ((uint4*)xb)[idx] = o;
        }
    } else if (b < G_CVT + G_HIST) {
        int e = (b - G_CVT) * 256 + tid;
        if (e < N_EDGES) atomicAdd(&cnt[dst[e]], 1);
    } else if (b < G_CVT + G_HIST + G_PREPW) {
        int idx = (b - G_CVT - G_HIST) * 256 + tid;   // 0..6143
        int layer = idx >> 11;
        const float* W = (layer == 0) ? W1 : (layer == 1) ? W2 : W3;
        int t = idx & 2047;
        int lane = t & 63, sc = t >> 6;
        int s = sc >> 3, c = sc & 7;
        int q = lane >> 4, m = lane & 15;
        int k0 = 32 * s + 8 * q, n0 = 16 * c + m;
        float w[8], h[8];
        #pragma unroll
        for (int j = 0; j < 8; ++j) {
            w[j] = W[(k0 + j) * F + n0];
            h[j] = bf16_rnd(w[j]);
        }
        uint4 uh, ul;
        uh.x = pk_bf16(h[0], h[1]); uh.y = pk_bf16(h[2], h[3]);
        uh.z = pk_bf16(h[4], h[5]); uh.w = pk_bf16(h[6], h[7]);
        ul.x = pk_bf16(w[0] - h[0], w[1] - h[1]); ul.y = pk_bf16(w[2] - h[2], w[3] - h[3]);
        ul.z = pk_bf16(w[4] - h[4], w[5] - h[5]); ul.w = pk_bf16(w[6] - h[6], w[7] - h[7]);
        Whi[idx] = uh;
        Wlo[idx] = ul;
    } else {
        int i = (b - G_CVT - G_HIST - G_PREPW) * 256 + tid;
        if (i < N_NODES) {
            int bi = batch[i];
            if (i == 0) {
                for (int g = 0; g <= bi; ++g) gs[g] = 0;
            } else {
                int bp = batch[i - 1];
                for (int g = bp + 1; g <= bi; ++g) gs[g] = i;
            }
            if (i == N_NODES - 1) {
                for (int g = bi + 1; g <= N_GRAPHS; ++g) gs[g] = N_NODES;
            }
        }
    }
}

// ================= CSR scan + fill + degree-sort =================
// scan1: also accumulates a 64-bin degree histogram (block-local LDS -> global dh)
__global__ __launch_bounds__(256) void k_scan1(const int* __restrict__ cnt, int* __restrict__ row_ptr,
                                               int* __restrict__ blksums, float* __restrict__ dinv,
                                               int* __restrict__ dh, int n) {
    __shared__ int s[256];
    __shared__ int dhl[64];
    int tid = threadIdx.x;
    int i = blockIdx.x * 256 + tid;
    if (tid < 64) dhl[tid] = 0;
    int v = (i < n) ? cnt[i] : 0;
    if (i < n) dinv[i] = rsqrtf((float)(v + 1));
    s[tid] = v;
    __syncthreads();
    if (i < n) atomicAdd(&dhl[v < 63 ? v : 63], 1);
    for (int off = 1; off < 256; off <<= 1) {
        int t = (tid >= off) ? s[tid - off] : 0;
        __syncthreads();
        s[tid] += t;
        __syncthreads();
    }
    if (i < n) row_ptr[i] = s[tid] - v;
    if (tid == 255) blksums[blockIdx.x] = s[255];
    __syncthreads();
    if (tid < 64 && dhl[tid] > 0) atomicAdd(&dh[tid], dhl[tid]);
}

// scan23: row_ptr fixup; block 0 additionally scans the 64-bin histogram (wave shuffle)
__global__ __launch_bounds__(256) void k_scan23(int* __restrict__ row_ptr, const int* __restrict__ blksums,
                                                const int* __restrict__ dh, int* __restrict__ dhoff,
                                                int* __restrict__ dcur, int n, int ne) {
    __shared__ int s[256];
    int tid = threadIdx.x;
    s[tid] = (tid < (int)blockIdx.x) ? blksums[tid] : 0;
    __syncthreads();
    for (int off = 128; off > 0; off >>= 1) {
        if (tid < off) s[tid] += s[tid + off];
        __syncthreads();
    }
    int base = s[0];
    int i = blockIdx.x * 256 + tid;
    if (i < n) row_ptr[i] += base;
    if (i == 0) row_ptr[n] = ne;
    if (blockIdx.x == 0 && tid < 64) {
        int v = dh[tid];
        int x = v;
        #pragma unroll
        for (int off = 1; off < 64; off <<= 1) {
            int t = __shfl_up(x, off, 64);
            if (tid >= off) x += t;
        }
        dhoff[tid] = x - v;   // exclusive prefix
        dcur[tid] = 0;
    }
}

#define G_FILL 2344
#define G_PLACE 196
// fill: CSR edge records; second grid partition: degree-sorted node placement
__global__ __launch_bounds__(256) void k_fill(const int* __restrict__ src, const int* __restrict__ dst,
                                              const int* __restrict__ row_ptr, int* __restrict__ cnt,
                                              const float* __restrict__ dinv,
                                              int2* __restrict__ esw,
                                              const int* __restrict__ dhoff, int* __restrict__ dcur,
                                              int* __restrict__ perm, int ne) {
    int b = blockIdx.x, tid = threadIdx.x;
    if (b < G_FILL) {
        int e = b * 256 + tid;
        if (e < ne) {
            int d = dst[e];
            int s = src[e];
            int pos = row_ptr[d] + atomicSub(&cnt[d], 1) - 1;
            esw[pos] = make_int2(s, __float_as_int(dinv[s]));
        }
    } else {
        int i = (b - G_FILL) * 256 + tid;
        if (i < N_NODES) {
            int deg = row_ptr[i + 1] - row_ptr[i];
            if (deg > 63) deg = 63;
            int slot = dhoff[deg] + atomicAdd(&dcur[deg], 1);
            perm[slot] = i;
        }
    }
}

// ============ fused aggregate-first layer: Hout = bf16(relu(Agg(Hin) @ W + b)) ============
// Degree-sorted: block processes 16 nodes of ≈equal degree (perm order) -> no intra-wave
// divergence waste, balanced barrier. One node per 16-lane group; per-group LDS edge staging
// (wave-internal, no barrier). 8-deep batched row loads. NO min-waves bound (r11/r15/r17).
// Phase 2: ds_read_b128 A-frags from bf16 Gb; 2 MFMAs/tile (W hi/lo). Scatter-store by perm.
#define TN 16
#define GP2 136
#define CAPG 64
__global__ __launch_bounds__(256) void k_fused(const int* __restrict__ row_ptr,
                                               const int2* __restrict__ esw,
                                               const float* __restrict__ dinv,
                                               const int* __restrict__ perm,
                                               const unsigned short* __restrict__ Hin,
                                               const uint4* __restrict__ Whi,
                                               const uint4* __restrict__ Wlo,
                                               const float* __restrict__ bias,
                                               unsigned short* __restrict__ Hout, int n) {
    __shared__ unsigned short Gb[TN * GP2];   // 4.25 KB
    __shared__ uint2 eLg[TN][CAPG];           // 8 KB
    __shared__ int nodeL[TN], begL[TN], endL[TN];
    __shared__ float ddl[TN];
    int tid = threadIdx.x;
    int d0 = blockIdx.x * TN;
    int grp = tid >> 4, sub = tid & 15;

    // ---- phase 0a: per-group node info ----
    if (tid < TN) {
        int slot = d0 + tid;
        int node = (slot < n) ? perm[slot] : -1;
        nodeL[tid] = node;
        if (node >= 0) {
            begL[tid] = row_ptr[node];
            endL[tid] = row_ptr[node + 1];
            ddl[tid] = dinv[node];
        } else {
            begL[tid] = 0; endL[tid] = 0; ddl[tid] = 0.f;
        }
    }
    __syncthreads();

    int node = nodeL[grp];
    int beg = begL[grp], end = endL[grp];
    int deg = end - beg;
    float dd = ddl[grp];

    // ---- phase 0b: per-group edge staging (same wave writes+reads its own rows) ----
    int degc = deg < CAPG ? deg : CAPG;
    for (int i = sub; i < degc; i += 16) eLg[grp][i] = ((const uint2*)esw)[beg + i];

    // ---- phase 1: gather ----
    float4 accL = make_float4(0.f, 0.f, 0.f, 0.f);
    float4 accH = make_float4(0.f, 0.f, 0.f, 0.f);
    if (node >= 0) {
        // self-loop first
        uint4 srow = ((const uint4*)(Hin + (size_t)node * F))[sub];
        float ws = dd * dd;
        accL.x = BF_LO(srow.x) * ws;
        accL.y = BF_HI(srow.x) * ws;
        accL.z = BF_LO(srow.y) * ws;
        accL.w = BF_HI(srow.y) * ws;
        accH.x = BF_LO(srow.z) * ws;
        accH.y = BF_HI(srow.z) * ws;
        accH.z = BF_LO(srow.w) * ws;
        accH.w = BF_HI(srow.w) * ws;
        for (int c = 0; c < deg; c += 8) {
            int sjs[8];
            #pragma unroll
            for (int j = 0; j < 8; ++j) {
                int e = c + j;
                int sj = node;
                if (e < deg) sj = (e < CAPG) ? (int)eLg[grp][e].x
                                             : ((const uint2*)esw)[beg + e].x;
                sjs[j] = sj;
            }
            uint4 rows[8];
            #pragma unroll
            for (int j = 0; j < 8; ++j)
                rows[j] = ((const uint4*)(Hin + (size_t)sjs[j] * F))[sub];
            #pragma unroll
            for (int j = 0; j < 8; ++j) {
                int e = c + j;
                float wj = 0.f;
                if (e < deg) {
                    unsigned wb = (e < CAPG) ? eLg[grp][e].y
                                             : (unsigned)((const uint2*)esw)[beg + e].y;
                    wj = __uint_as_float(wb) * dd;
                }
                accL.x = fmaf(BF_LO(rows[j].x), wj, accL.x);
                accL.y = fmaf(BF_HI(rows[j].x), wj, accL.y);
                accL.z = fmaf(BF_LO(rows[j].y), wj, accL.z);
                accL.w = fmaf(BF_HI(rows[j].y), wj, accL.w);
                accH.x = fmaf(BF_LO(rows[j].z), wj, accH.x);
                accH.y = fmaf(BF_HI(rows[j].z), wj, accH.y);
                accH.z = fmaf(BF_LO(rows[j].w), wj, accH.z);
                accH.w = fmaf(BF_HI(rows[j].w), wj, accH.w);
            }
        }
    }
    {
        uint4 o;
        o.x = pk_bf16(accL.x, accL.y);
        o.y = pk_bf16(accL.z, accL.w);
        o.z = pk_bf16(accH.x, accH.y);
        o.w = pk_bf16(accH.z, accH.w);
        *(uint4*)&Gb[grp * GP2 + 8 * sub] = o;
    }
    __syncthreads();

    // ---- phase 2: MFMA. 16 rows; wave handles col tiles 2*wave, 2*wave+1 ----
    int wave = tid >> 6, lane = tid & 63;
    int q = lane >> 4, m = lane & 15;
    f32x4 acc[2];
    acc[0] = (f32x4){0.f, 0.f, 0.f, 0.f};
    acc[1] = (f32x4){0.f, 0.f, 0.f, 0.f};
    #pragma unroll
    for (int s = 0; s < 4; ++s) {
        U4H8 a;
        a.u = *(const uint4*)&Gb[m * GP2 + 32 * s + 8 * q];
        #pragma unroll
        for (int cc = 0; cc < 2; ++cc) {
            int c = wave * 2 + cc;
            U4H8 bh, bl;
            bh.u = Whi[(s * 8 + c) * 64 + lane];
            bl.u = Wlo[(s * 8 + c) * 64 + lane];
            acc[cc] = __builtin_amdgcn_mfma_f32_16x16x32_bf16(a.h, bh.h, acc[cc], 0, 0, 0);
            acc[cc] = __builtin_amdgcn_mfma_f32_16x16x32_bf16(a.h, bl.h, acc[cc], 0, 0, 0);
        }
    }
    __syncthreads();

    // ---- epilogue: bias + relu -> Gb (transpose), scatter-store rows by perm ----
    #pragma unroll
    for (int cc = 0; cc < 2; ++cc) {
        int c = wave * 2 + cc;
        float bb = bias[16 * c + m];
        #pragma unroll
        for (int r = 0; r < 4; ++r)
            Gb[(4 * q + r) * GP2 + 16 * c + m] = bf16_1(fmaxf(acc[cc][r] + bb, 0.f));
    }
    __syncthreads();
    {
        int row = tid >> 4, c8 = tid & 15;   // 256 threads = 16 rows x 16 uint4
        int onode = nodeL[row];
        if (onode >= 0) {
            uint4 o = *(const uint4*)&Gb[row * GP2 + c8 * 8];
            ((uint4*)(Hout + (size_t)onode * F))[c8] = o;
        }
    }
}

// ============ fused pool (segment mean via precomputed bounds) + FC head ============
__global__ __launch_bounds__(256) void k_pool_fc(const unsigned short* __restrict__ Hb,
                                                 const int* __restrict__ gs,
                                                 const float* __restrict__ Wf1,
                                                 const float* __restrict__ bf1,
                                                 const float* __restrict__ Wf2,
                                                 const float* __restrict__ bf2,
                                                 float* __restrict__ out) {
    int g = blockIdx.x;
    int tid = threadIdx.x;
    int start = gs[g], end = gs[g + 1];

    __shared__ float hs[4][F];
    __shared__ float hg[F];
    int wv = tid >> 6, lane = tid & 63;
    int half = lane >> 5, sub = lane & 31;
    float4 a = make_float4(0.f, 0.f, 0.f, 0.f);
    for (int i = start + wv * 2 + half; i < end; i += 8) {
        uint2 v = ((const uint2*)(Hb + (size_t)i * F))[sub];
        a.x += BF_LO(v.x); a.y += BF_HI(v.x);
        a.z += BF_LO(v.y); a.w += BF_HI(v.y);
    }
    a.x += __shfl_xor(a.x, 32, 64);
    a.y += __shfl_xor(a.y, 32, 64);
    a.z += __shfl_xor(a.z, 32, 64);
    a.w += __shfl_xor(a.w, 32, 64);
    if (half == 0) ((float4*)hs[wv])[sub] = a;
    __syncthreads();
    if (tid < F) {
        float inv = 1.0f / (float)((end - start) > 0 ? (end - start) : 1);
        hg[tid] = (hs[0][tid] + hs[1][tid] + hs[2][tid] + hs[3][tid]) * inv;
    }
    __syncthreads();
    if (tid < 64) {
        float acc = bf1[tid];
        #pragma unroll 4
        for (int f = 0; f < F; ++f) acc = fmaf(hg[f], Wf1[f * 64 + tid], acc);
        float v = fmaxf(acc, 0.f) * Wf2[tid];
        #pragma unroll
        for (int off = 32; off > 0; off >>= 1) v += __shfl_down(v, off, 64);
        if (tid == 0) out[g] = v + bf2[0];
    }
}

extern "C" void kernel_launch(void* const* d_in, const int* in_sizes, int n_in,
                              void* d_out, int out_size, void* d_ws, size_t ws_size,
                              hipStream_t stream) {
    const float* x    = (const float*)d_in[0];
    const int* eidx   = (const int*)d_in[1];
    const int* batch  = (const int*)d_in[2];
    const float* W1   = (const float*)d_in[3];
    const float* b1   = (const float*)d_in[4];
    const float* W2   = (const float*)d_in[5];
    const float* b2   = (const float*)d_in[6];
    const float* W3   = (const float*)d_in[7];
    const float* b3   = (const float*)d_in[8];
    const float* Wf1  = (const float*)d_in[9];
    const float* bf1  = (const float*)d_in[10];
    const float* Wf2  = (const float*)d_in[11];
    const float* bf2  = (const float*)d_in[12];
    float* out = (float*)d_out;

    const int* src = eidx;
    const int* dst = eidx + N_EDGES;

    char* p = (char*)d_ws;
    unsigned short* Xb  = (unsigned short*)p;  p += (size_t)N_NODES * F * 2;
    unsigned short* H1  = (unsigned short*)p;  p += (size_t)N_NODES * F * 2;
    unsigned short* H2  = (unsigned short*)p;  p += (size_t)N_NODES * F * 2;
    unsigned short* H3  = (unsigned short*)p;  p += (size_t)N_NODES * F * 2;
    int2* esw   = (int2*)p;    p += (size_t)N_EDGES * sizeof(int2);
    uint4* Whi  = (uint4*)p;   p += (size_t)3 * 2048 * sizeof(uint4);
    uint4* Wlo  = (uint4*)p;   p += (size_t)3 * 2048 * sizeof(uint4);
    float* dinv = (float*)p;   p += (size_t)N_NODES * sizeof(float);
    int* cnt     = (int*)p;    p += (size_t)N_NODES * sizeof(int);
    int* dh      = (int*)p;    p += 64 * sizeof(int);          // zeroed with cnt (adjacent)
    int* row_ptr = (int*)p;    p += (size_t)(N_NODES + 1) * sizeof(int);
    int* blksums = (int*)p;    p += 256 * sizeof(int);
    int* gs      = (int*)p;    p += (size_t)(N_GRAPHS + 1) * sizeof(int);
    int* dhoff   = (int*)p;    p += 64 * sizeof(int);
    int* dcur    = (int*)p;    p += 64 * sizeof(int);
    int* perm    = (int*)p;    p += (size_t)N_NODES * sizeof(int);

    dim3 b256(256);
    int gNodes = (N_NODES + 255) / 256;           // 196
    int gFused = (N_NODES + TN - 1) / TN;         // 3125

    // ---- prep (cvt + hist + prepW + pool bounds); cnt+dh zeroed first ----
    hipMemsetAsync(cnt, 0, ((size_t)N_NODES + 64) * sizeof(int), stream);
    k_prep<<<G_CVT + G_HIST + G_PREPW + G_BND, b256, 0, stream>>>(x, Xb, dst, cnt, W1, W2, W3,
                                                                  Whi, Wlo, batch, gs);

    // ---- CSR scan + fill + degree-sort placement ----
    k_scan1<<<gNodes, b256, 0, stream>>>(cnt, row_ptr, blksums, dinv, dh, N_NODES);
    k_scan23<<<gNodes, b256, 0, stream>>>(row_ptr, blksums, dh, dhoff, dcur, N_NODES, N_EDGES);
    k_fill<<<G_FILL + G_PLACE, b256, 0, stream>>>(src, dst, row_ptr, cnt, dinv, esw,
                                                  dhoff, dcur, perm, N_EDGES);

    // ---- 3 aggregate-first fused layers (degree-sorted) ----
    k_fused<<<gFused, b256, 0, stream>>>(row_ptr, esw, dinv, perm, Xb, Whi,        Wlo,        b1, H1, N_NODES);
    k_fused<<<gFused, b256, 0, stream>>>(row_ptr, esw, dinv, perm, H1, Whi + 2048, Wlo + 2048, b2, H2, N_NODES);
    k_fused<<<gFused, b256, 0, stream>>>(row_ptr, esw, dinv, perm, H2, Whi + 4096, Wlo + 4096, b3, H3, N_NODES);

    // ---- pool + FC ----
    k_pool_fc<<<N_GRAPHS, b256, 0, stream>>>(H3, gs, Wf1, bf1, Wf2, bf2, out);
}

// Round 21
// 263.433 us; speedup vs baseline: 1.5722x; 1.5722x over previous
//
#include <hip/hip_runtime.h>

#define N_NODES 50000
#define N_EDGES 600000
#define N_GRAPHS 500
#define F 128

typedef short bf16x8 __attribute__((ext_vector_type(8)));
typedef float f32x4 __attribute__((ext_vector_type(4)));
union U4H8 { uint4 u; bf16x8 h; };

// ---- bf16 helpers (RNE) ----
__device__ inline unsigned pk_bf16(float a, float b) {
    unsigned ua = __float_as_uint(a), ub = __float_as_uint(b);
    ua = (ua + 0x7fffu + ((ua >> 16) & 1u)) >> 16;
    ub = (ub + 0x7fffu + ((ub >> 16) & 1u)) >> 16;
    return ua | (ub << 16);
}
__device__ inline float bf16_rnd(float x) {
    unsigned u = __float_as_uint(x);
    u = (u + 0x7fffu + ((u >> 16) & 1u)) & 0xffff0000u;
    return __uint_as_float(u);
}
__device__ inline unsigned short bf16_1(float a) {
    unsigned ua = __float_as_uint(a);
    return (unsigned short)((ua + 0x7fffu + ((ua >> 16) & 1u)) >> 16);
}
#define BF_LO(u) __uint_as_float((u) << 16)
#define BF_HI(u) __uint_as_float((u) & 0xffff0000u)

#define G_CVT  3125
#define G_HIST 2344
#define G_PREPW 24
#define G_BND  196

// ====== merged prep: x->bf16 | dst histogram | W split-pack | pool segment bounds ======
__global__ __launch_bounds__(256) void k_prep(const float* __restrict__ x, unsigned short* __restrict__ xb,
                                              const int* __restrict__ dst, int* __restrict__ cnt,
                                              const float* __restrict__ W1, const float* __restrict__ W2,
                                              const float* __restrict__ W3,
                                              uint4* __restrict__ Whi, uint4* __restrict__ Wlo,
                                              const int* __restrict__ batch, int* __restrict__ gs) {
    int b = blockIdx.x, tid = threadIdx.x;
    if (b < G_CVT) {
        int idx = b * 256 + tid;
        if (idx < N_NODES * F / 8) {
            const float4* xr = (const float4*)(x + (size_t)idx * 8);
            float4 a = xr[0], c = xr[1];
            uint4 o;
            o.x = pk_bf16(a.x, a.y); o.y = pk_bf16(a.z, a.w);
            o.z = pk_bf16(c.x, c.y); o.w = pk_bf16(c.z, c.w);
            ((uint4*)xb)[idx] = o;
        }
    } else if (b < G_CVT + G_HIST) {
        int e = (b - G_CVT) * 256 + tid;
        if (e < N_EDGES) atomicAdd(&cnt[dst[e]], 1);
    } else if (b < G_CVT + G_HIST + G_PREPW) {
        int idx = (b - G_CVT - G_HIST) * 256 + tid;   // 0..6143
        int layer = idx >> 11;
        const float* W = (layer == 0) ? W1 : (layer == 1) ? W2 : W3;
        int t = idx & 2047;
        int lane = t & 63, sc = t >> 6;
        int s = sc >> 3, c = sc & 7;
        int q = lane >> 4, m = lane & 15;
        int k0 = 32 * s + 8 * q, n0 = 16 * c + m;
        float w[8], h[8];
        #pragma unroll
        for (int j = 0; j < 8; ++j) {
            w[j] = W[(k0 + j) * F + n0];
            h[j] = bf16_rnd(w[j]);
        }
        uint4 uh, ul;
        uh.x = pk_bf16(h[0], h[1]); uh.y = pk_bf16(h[2], h[3]);
        uh.z = pk_bf16(h[4], h[5]); uh.w = pk_bf16(h[6], h[7]);
        ul.x = pk_bf16(w[0] - h[0], w[1] - h[1]); ul.y = pk_bf16(w[2] - h[2], w[3] - h[3]);
        ul.z = pk_bf16(w[4] - h[4], w[5] - h[5]); ul.w = pk_bf16(w[6] - h[6], w[7] - h[7]);
        Whi[idx] = uh;
        Wlo[idx] = ul;
    } else {
        int i = (b - G_CVT - G_HIST - G_PREPW) * 256 + tid;
        if (i < N_NODES) {
            int bi = batch[i];
            if (i == 0) {
                for (int g = 0; g <= bi; ++g) gs[g] = 0;
            } else {
                int bp = batch[i - 1];
                for (int g = bp + 1; g <= bi; ++g) gs[g] = i;
            }
            if (i == N_NODES - 1) {
                for (int g = bi + 1; g <= N_GRAPHS; ++g) gs[g] = N_NODES;
            }
        }
    }
}

// ================= CSR scan + fill + degree-sort =================
__global__ __launch_bounds__(256) void k_scan1(const int* __restrict__ cnt, int* __restrict__ row_ptr,
                                               int* __restrict__ blksums, float* __restrict__ dinv,
                                               int* __restrict__ dh, int n) {
    __shared__ int s[256];
    __shared__ int dhl[64];
    int tid = threadIdx.x;
    int i = blockIdx.x * 256 + tid;
    if (tid < 64) dhl[tid] = 0;
    int v = (i < n) ? cnt[i] : 0;
    if (i < n) dinv[i] = rsqrtf((float)(v + 1));
    s[tid] = v;
    __syncthreads();
    if (i < n) atomicAdd(&dhl[v < 63 ? v : 63], 1);
    for (int off = 1; off < 256; off <<= 1) {
        int t = (tid >= off) ? s[tid - off] : 0;
        __syncthreads();
        s[tid] += t;
        __syncthreads();
    }
    if (i < n) row_ptr[i] = s[tid] - v;
    if (tid == 255) blksums[blockIdx.x] = s[255];
    __syncthreads();
    if (tid < 64 && dhl[tid] > 0) atomicAdd(&dh[tid], dhl[tid]);
}

__global__ __launch_bounds__(256) void k_scan23(int* __restrict__ row_ptr, const int* __restrict__ blksums,
                                                const int* __restrict__ dh, int* __restrict__ dhoff,
                                                int* __restrict__ dcur, int n, int ne) {
    __shared__ int s[256];
    int tid = threadIdx.x;
    s[tid] = (tid < (int)blockIdx.x) ? blksums[tid] : 0;
    __syncthreads();
    for (int off = 128; off > 0; off >>= 1) {
        if (tid < off) s[tid] += s[tid + off];
        __syncthreads();
    }
    int base = s[0];
    int i = blockIdx.x * 256 + tid;
    if (i < n) row_ptr[i] += base;
    if (i == 0) row_ptr[n] = ne;
    if (blockIdx.x == 0 && tid < 64) {
        int v = dh[tid];
        int x = v;
        #pragma unroll
        for (int off = 1; off < 64; off <<= 1) {
            int t = __shfl_up(x, off, 64);
            if (tid >= off) x += t;
        }
        dhoff[tid] = x - v;   // exclusive prefix
        dcur[tid] = 0;
    }
}

#define G_FILL 2344
#define G_PLACE 196
// fill: CSR edge records; placement: block-aggregated degree-sort (ONE global atomic
// per (block,bin) — r20 lesson: per-node atomics on 64 counters serialize cross-XCD)
__global__ __launch_bounds__(256) void k_fill(const int* __restrict__ src, const int* __restrict__ dst,
                                              const int* __restrict__ row_ptr, int* __restrict__ cnt,
                                              const float* __restrict__ dinv,
                                              int2* __restrict__ esw,
                                              const int* __restrict__ dhoff, int* __restrict__ dcur,
                                              int* __restrict__ perm, int ne) {
    __shared__ int lh[64];
    __shared__ int lbase[64];
    int b = blockIdx.x, tid = threadIdx.x;
    if (b < G_FILL) {
        int e = b * 256 + tid;
        if (e < ne) {
            int d = dst[e];
            int s = src[e];
            int pos = row_ptr[d] + atomicSub(&cnt[d], 1) - 1;
            esw[pos] = make_int2(s, __float_as_int(dinv[s]));
        }
    } else {
        int i = (b - G_FILL) * 256 + tid;
        if (tid < 64) lh[tid] = 0;
        __syncthreads();
        int deg = 0, rank = 0;
        bool valid = (i < N_NODES);
        if (valid) {
            deg = row_ptr[i + 1] - row_ptr[i];
            if (deg > 63) deg = 63;
            rank = atomicAdd(&lh[deg], 1);          // LDS atomic: cheap
        }
        __syncthreads();
        if (tid < 64 && lh[tid] > 0)
            lbase[tid] = atomicAdd(&dcur[tid], lh[tid]);   // one global atomic per bin
        __syncthreads();
        if (valid) perm[dhoff[deg] + lbase[deg] + rank] = i;
    }
}

// ============ fused aggregate-first layer: Hout = bf16(relu(Agg(Hin) @ W + b)) ============
// Degree-sorted: block processes 16 nodes of ≈equal degree (perm order). One node per
// 16-lane group; per-group LDS edge staging; 8-deep batched row loads. NO min-waves bound.
#define TN 16
#define GP2 136
#define CAPG 64
__global__ __launch_bounds__(256) void k_fused(const int* __restrict__ row_ptr,
                                               const int2* __restrict__ esw,
                                               const float* __restrict__ dinv,
                                               const int* __restrict__ perm,
                                               const unsigned short* __restrict__ Hin,
                                               const uint4* __restrict__ Whi,
                                               const uint4* __restrict__ Wlo,
                                               const float* __restrict__ bias,
                                               unsigned short* __restrict__ Hout, int n) {
    __shared__ unsigned short Gb[TN * GP2];   // 4.25 KB
    __shared__ uint2 eLg[TN][CAPG];           // 8 KB
    __shared__ int nodeL[TN], begL[TN], endL[TN];
    __shared__ float ddl[TN];
    int tid = threadIdx.x;
    int d0 = blockIdx.x * TN;
    int grp = tid >> 4, sub = tid & 15;

    if (tid < TN) {
        int slot = d0 + tid;
        int node = (slot < n) ? perm[slot] : -1;
        nodeL[tid] = node;
        if (node >= 0) {
            begL[tid] = row_ptr[node];
            endL[tid] = row_ptr[node + 1];
            ddl[tid] = dinv[node];
        } else {
            begL[tid] = 0; endL[tid] = 0; ddl[tid] = 0.f;
        }
    }
    __syncthreads();

    int node = nodeL[grp];
    int beg = begL[grp], end = endL[grp];
    int deg = end - beg;
    float dd = ddl[grp];

    int degc = deg < CAPG ? deg : CAPG;
    for (int i = sub; i < degc; i += 16) eLg[grp][i] = ((const uint2*)esw)[beg + i];

    float4 accL = make_float4(0.f, 0.f, 0.f, 0.f);
    float4 accH = make_float4(0.f, 0.f, 0.f, 0.f);
    if (node >= 0) {
        uint4 srow = ((const uint4*)(Hin + (size_t)node * F))[sub];
        float ws = dd * dd;
        accL.x = BF_LO(srow.x) * ws;
        accL.y = BF_HI(srow.x) * ws;
        accL.z = BF_LO(srow.y) * ws;
        accL.w = BF_HI(srow.y) * ws;
        accH.x = BF_LO(srow.z) * ws;
        accH.y = BF_HI(srow.z) * ws;
        accH.z = BF_LO(srow.w) * ws;
        accH.w = BF_HI(srow.w) * ws;
        for (int c = 0; c < deg; c += 8) {
            int sjs[8];
            #pragma unroll
            for (int j = 0; j < 8; ++j) {
                int e = c + j;
                int sj = node;
                if (e < deg) sj = (e < CAPG) ? (int)eLg[grp][e].x
                                             : ((const uint2*)esw)[beg + e].x;
                sjs[j] = sj;
            }
            uint4 rows[8];
            #pragma unroll
            for (int j = 0; j < 8; ++j)
                rows[j] = ((const uint4*)(Hin + (size_t)sjs[j] * F))[sub];
            #pragma unroll
            for (int j = 0; j < 8; ++j) {
                int e = c + j;
                float wj = 0.f;
                if (e < deg) {
                    unsigned wb = (e < CAPG) ? eLg[grp][e].y
                                             : (unsigned)((const uint2*)esw)[beg + e].y;
                    wj = __uint_as_float(wb) * dd;
                }
                accL.x = fmaf(BF_LO(rows[j].x), wj, accL.x);
                accL.y = fmaf(BF_HI(rows[j].x), wj, accL.y);
                accL.z = fmaf(BF_LO(rows[j].y), wj, accL.z);
                accL.w = fmaf(BF_HI(rows[j].y), wj, accL.w);
                accH.x = fmaf(BF_LO(rows[j].z), wj, accH.x);
                accH.y = fmaf(BF_HI(rows[j].z), wj, accH.y);
                accH.z = fmaf(BF_LO(rows[j].w), wj, accH.z);
                accH.w = fmaf(BF_HI(rows[j].w), wj, accH.w);
            }
        }
    }
    {
        uint4 o;
        o.x = pk_bf16(accL.x, accL.y);
        o.y = pk_bf16(accL.z, accL.w);
        o.z = pk_bf16(accH.x, accH.y);
        o.w = pk_bf16(accH.z, accH.w);
        *(uint4*)&Gb[grp * GP2 + 8 * sub] = o;
    }
    __syncthreads();

    // ---- phase 2: MFMA ----
    int wave = tid >> 6, lane = tid & 63;
    int q = lane >> 4, m = lane & 15;
    f32x4 acc[2];
    acc[0] = (f32x4){0.f, 0.f, 0.f, 0.f};
    acc[1] = (f32x4){0.f, 0.f, 0.f, 0.f};
    #pragma unroll
    for (int s = 0; s < 4; ++s) {
        U4H8 a;
        a.u = *(const uint4*)&Gb[m * GP2 + 32 * s + 8 * q];
        #pragma unroll
        for (int cc = 0; cc < 2; ++cc) {
            int c = wave * 2 + cc;
            U4H8 bh, bl;
            bh.u = Whi[(s * 8 + c) * 64 + lane];
            bl.u = Wlo[(s * 8 + c) * 64 + lane];
            acc[cc] = __builtin_amdgcn_mfma_f32_16x16x32_bf16(a.h, bh.h, acc[cc], 0, 0, 0);
            acc[cc] = __builtin_amdgcn_mfma_f32_16x16x32_bf16(a.h, bl.h, acc[cc], 0, 0, 0);
        }
    }
    __syncthreads();

    // ---- epilogue ----
    #pragma unroll
    for (int cc = 0; cc < 2; ++cc) {
        int c = wave * 2 + cc;
        float bb = bias[16 * c + m];
        #pragma unroll
        for (int r = 0; r < 4; ++r)
            Gb[(4 * q + r) * GP2 + 16 * c + m] = bf16_1(fmaxf(acc[cc][r] + bb, 0.f));
    }
    __syncthreads();
    {
        int row = tid >> 4, c8 = tid & 15;
        int onode = nodeL[row];
        if (onode >= 0) {
            uint4 o = *(const uint4*)&Gb[row * GP2 + c8 * 8];
            ((uint4*)(Hout + (size_t)onode * F))[c8] = o;
        }
    }
}

// ============ fused pool (segment mean via precomputed bounds) + FC head ============
__global__ __launch_bounds__(256) void k_pool_fc(const unsigned short* __restrict__ Hb,
                                                 const int* __restrict__ gs,
                                                 const float* __restrict__ Wf1,
                                                 const float* __restrict__ bf1,
                                                 const float* __restrict__ Wf2,
                                                 const float* __restrict__ bf2,
                                                 float* __restrict__ out) {
    int g = blockIdx.x;
    int tid = threadIdx.x;
    int start = gs[g], end = gs[g + 1];

    __shared__ float hs[4][F];
    __shared__ float hg[F];
    int wv = tid >> 6, lane = tid & 63;
    int half = lane >> 5, sub = lane & 31;
    float4 a = make_float4(0.f, 0.f, 0.f, 0.f);
    for (int i = start + wv * 2 + half; i < end; i += 8) {
        uint2 v = ((const uint2*)(Hb + (size_t)i * F))[sub];
        a.x += BF_LO(v.x); a.y += BF_HI(v.x);
        a.z += BF_LO(v.y); a.w += BF_HI(v.y);
    }
    a.x += __shfl_xor(a.x, 32, 64);
    a.y += __shfl_xor(a.y, 32, 64);
    a.z += __shfl_xor(a.z, 32, 64);
    a.w += __shfl_xor(a.w, 32, 64);
    if (half == 0) ((float4*)hs[wv])[sub] = a;
    __syncthreads();
    if (tid < F) {
        float inv = 1.0f / (float)((end - start) > 0 ? (end - start) : 1);
        hg[tid] = (hs[0][tid] + hs[1][tid] + hs[2][tid] + hs[3][tid]) * inv;
    }
    __syncthreads();
    if (tid < 64) {
        float acc = bf1[tid];
        #pragma unroll 4
        for (int f = 0; f < F; ++f) acc = fmaf(hg[f], Wf1[f * 64 + tid], acc);
        float v = fmaxf(acc, 0.f) * Wf2[tid];
        #pragma unroll
        for (int off = 32; off > 0; off >>= 1) v += __shfl_down(v, off, 64);
        if (tid == 0) out[g] = v + bf2[0];
    }
}

extern "C" void kernel_launch(void* const* d_in, const int* in_sizes, int n_in,
                              void* d_out, int out_size, void* d_ws, size_t ws_size,
                              hipStream_t stream) {
    const float* x    = (const float*)d_in[0];
    const int* eidx   = (const int*)d_in[1];
    const int* batch  = (const int*)d_in[2];
    const float* W1   = (const float*)d_in[3];
    const float* b1   = (const float*)d_in[4];
    const float* W2   = (const float*)d_in[5];
    const float* b2   = (const float*)d_in[6];
    const float* W3   = (const float*)d_in[7];
    const float* b3   = (const float*)d_in[8];
    const float* Wf1  = (const float*)d_in[9];
    const float* bf1  = (const float*)d_in[10];
    const float* Wf2  = (const float*)d_in[11];
    const float* bf2  = (const float*)d_in[12];
    float* out = (float*)d_out;

    const int* src = eidx;
    const int* dst = eidx + N_EDGES;

    char* p = (char*)d_ws;
    unsigned short* Xb  = (unsigned short*)p;  p += (size_t)N_NODES * F * 2;
    unsigned short* H1  = (unsigned short*)p;  p += (size_t)N_NODES * F * 2;
    unsigned short* H2  = (unsigned short*)p;  p += (size_t)N_NODES * F * 2;
    unsigned short* H3  = (unsigned short*)p;  p += (size_t)N_NODES * F * 2;
    int2* esw   = (int2*)p;    p += (size_t)N_EDGES * sizeof(int2);
    uint4* Whi  = (uint4*)p;   p += (size_t)3 * 2048 * sizeof(uint4);
    uint4* Wlo  = (uint4*)p;   p += (size_t)3 * 2048 * sizeof(uint4);
    float* dinv = (float*)p;   p += (size_t)N_NODES * sizeof(float);
    int* cnt     = (int*)p;    p += (size_t)N_NODES * sizeof(int);
    int* dh      = (int*)p;    p += 64 * sizeof(int);          // zeroed with cnt (adjacent)
    int* row_ptr = (int*)p;    p += (size_t)(N_NODES + 1) * sizeof(int);
    int* blksums = (int*)p;    p += 256 * sizeof(int);
    int* gs      = (int*)p;    p += (size_t)(N_GRAPHS + 1) * sizeof(int);
    int* dhoff   = (int*)p;    p += 64 * sizeof(int);
    int* dcur    = (int*)p;    p += 64 * sizeof(int);
    int* perm    = (int*)p;    p += (size_t)N_NODES * sizeof(int);

    dim3 b256(256);
    int gNodes = (N_NODES + 255) / 256;           // 196
    int gFused = (N_NODES + TN - 1) / TN;         // 3125

    // ---- prep (cvt + hist + prepW + pool bounds); cnt+dh zeroed first ----
    hipMemsetAsync(cnt, 0, ((size_t)N_NODES + 64) * sizeof(int), stream);
    k_prep<<<G_CVT + G_HIST + G_PREPW + G_BND, b256, 0, stream>>>(x, Xb, dst, cnt, W1, W2, W3,
                                                                  Whi, Wlo, batch, gs);

    // ---- CSR scan + fill + degree-sort placement ----
    k_scan1<<<gNodes, b256, 0, stream>>>(cnt, row_ptr, blksums, dinv, dh, N_NODES);
    k_scan23<<<gNodes, b256, 0, stream>>>(row_ptr, blksums, dh, dhoff, dcur, N_NODES, N_EDGES);
    k_fill<<<G_FILL + G_PLACE, b256, 0, stream>>>(src, dst, row_ptr, cnt, dinv, esw,
                                                  dhoff, dcur, perm, N_EDGES);

    // ---- 3 aggregate-first fused layers (degree-sorted) ----
    k_fused<<<gFused, b256, 0, stream>>>(row_ptr, esw, dinv, perm, Xb, Whi,        Wlo,        b1, H1, N_NODES);
    k_fused<<<gFused, b256, 0, stream>>>(row_ptr, esw, dinv, perm, H1, Whi + 2048, Wlo + 2048, b2, H2, N_NODES);
    k_fused<<<gFused, b256, 0, stream>>>(row_ptr, esw, dinv, perm, H2, Whi + 4096, Wlo + 4096, b3, H3, N_NODES);

    // ---- pool + FC ----
    k_pool_fc<<<N_GRAPHS, b256, 0, stream>>>(H3, gs, Wf1, bf1, Wf2, bf2, out);
}